// Round 7
// baseline (223.196 us; speedup 1.0000x reference)
//
#include <hip/hip_runtime.h>
#include <hip/hip_fp16.h>

#define NBCAP 256          // max buckets (static LDS arrays)
#define BSHIFT 10          // 1024 nodes per bucket
#define BSZ (1 << BSHIFT)
#define NPW 4              // nodes per wave in aggregate

typedef _Float16 f16x8 __attribute__((ext_vector_type(8)));
typedef float f32x4 __attribute__((ext_vector_type(4)));

// ---------------- k0: init bucket cursors to padded bases ----------------
__global__ __launch_bounds__(256) void init_cursors_kernel(
    int* __restrict__ curS, int* __restrict__ curD, int nb, int capS, int capD)
{
    int i = blockIdx.x * 256 + threadIdx.x;
    if (i < nb) { curS[i] = i * capS; curD[i] = i * capD; }
}

// ---------------- k1: partition edges by src-bucket and dst-bucket ----------------
// srcStage entry: local src id (ushort). dstStage entry: (dstLocal<<22)|src.
__global__ __launch_bounds__(256) void partition_kernel(
    const int* __restrict__ src, const int* __restrict__ dst,
    int* __restrict__ curS, int* __restrict__ curD,
    unsigned short* __restrict__ srcStage, unsigned* __restrict__ dstStage, int e)
{
    __shared__ int hS[NBCAP], hD[NBCAP], bS[NBCAP], bD[NBCAP];
    int tid = threadIdx.x;
    for (int i = tid; i < NBCAP; i += 256) { hS[i] = 0; hD[i] = 0; }
    __syncthreads();
    int blockBase = blockIdx.x * 4096;
    int s[16], d[16]; short rS[16], rD[16];
    #pragma unroll
    for (int k = 0; k < 16; ++k) {
        int i = blockBase + k * 256 + tid;
        if (i < e) {
            s[k] = src[i]; d[k] = dst[i];
            rS[k] = (short)atomicAdd(&hS[s[k] >> BSHIFT], 1);
            rD[k] = (short)atomicAdd(&hD[d[k] >> BSHIFT], 1);
        }
    }
    __syncthreads();
    for (int i = tid; i < NBCAP; i += 256) {
        bS[i] = hS[i] ? atomicAdd(&curS[i], hS[i]) : 0;
        bD[i] = hD[i] ? atomicAdd(&curD[i], hD[i]) : 0;
    }
    __syncthreads();
    #pragma unroll
    for (int k = 0; k < 16; ++k) {
        int i = blockBase + k * 256 + tid;
        if (i < e) {
            srcStage[bS[s[k] >> BSHIFT] + (int)rS[k]] = (unsigned short)(s[k] & (BSZ - 1));
            dstStage[bD[d[k] >> BSHIFT] + (int)rD[k]] =
                ((unsigned)(d[k] & (BSZ - 1)) << 22) | (unsigned)s[k];
        }
    }
}

// ---------------- k2: exact dst-bucket bases from cursors (single block) ----------------
__global__ __launch_bounds__(256) void bucket_scan_kernel(
    const int* __restrict__ curD, int* __restrict__ ebase,
    int* __restrict__ off, int nb, int capD, int n, int e)
{
    __shared__ int lds[256];
    int tid = threadIdx.x;
    int v = (tid < nb) ? (curD[tid] - tid * capD) : 0;
    lds[tid] = v;
    __syncthreads();
    for (int o = 1; o < 256; o <<= 1) {
        int a = (tid >= o) ? lds[tid - o] : 0;
        __syncthreads();
        lds[tid] += a;
        __syncthreads();
    }
    if (tid < nb) ebase[tid] = lds[tid] - v;
    if (tid == 0) { ebase[nb] = e; off[n] = e; }
}

// ---------------- k3: per-dst-bucket: din hist + CSR offsets + ndst + esrc scatter ----------------
__global__ __launch_bounds__(256) void csr_build_kernel(
    const unsigned* __restrict__ dstStage, const int* __restrict__ curD,
    const int* __restrict__ ebase, int capD,
    int* __restrict__ off, float* __restrict__ ndst, int* __restrict__ esrc, int n)
{
    __shared__ int cnt[BSZ];
    __shared__ int wsum[256];
    int b = blockIdx.x, tid = threadIdx.x;
    int nodeBase = b << BSHIFT;
    int nloc = min(BSZ, n - nodeBase);
    int sbeg = b * capD;
    int send = curD[b];
    int ebeg = ebase[b];
    for (int i = tid; i < BSZ; i += 256) cnt[i] = 0;
    __syncthreads();
    for (int e = sbeg + tid; e < send; e += 256)
        atomicAdd(&cnt[dstStage[e] >> 22], 1);
    __syncthreads();
    int c0 = cnt[tid * 4], c1 = cnt[tid * 4 + 1], c2 = cnt[tid * 4 + 2], c3 = cnt[tid * 4 + 3];
    int tsum = c0 + c1 + c2 + c3;
    wsum[tid] = tsum;
    __syncthreads();
    for (int o = 1; o < 256; o <<= 1) {
        int a = (tid >= o) ? wsum[tid - o] : 0;
        __syncthreads();
        wsum[tid] += a;
        __syncthreads();
    }
    int excl = wsum[tid] - tsum;
    int pj[4] = { excl, excl + c0, excl + c0 + c1, excl + c0 + c1 + c2 };
    int cj[4] = { c0, c1, c2, c3 };
    #pragma unroll
    for (int j = 0; j < 4; ++j) {
        int node = tid * 4 + j;
        if (node < nloc) {
            off[nodeBase + node]  = ebeg + pj[j];
            ndst[nodeBase + node] = rsqrtf((float)max(cj[j], 1));
        }
        cnt[node] = pj[j];   // becomes LDS cursor
    }
    __syncthreads();
    for (int e = sbeg + tid; e < send; e += 256) {
        unsigned u = dstStage[e];
        int lp = atomicAdd(&cnt[u >> 22], 1);
        esrc[ebeg + lp] = (int)(u & 0x3FFFFFu);
    }
}

// ---------------- k4: per-src-bucket: dout hist -> nsrc ----------------
__global__ __launch_bounds__(256) void dout_norm_kernel(
    const unsigned short* __restrict__ srcStage, const int* __restrict__ curS, int capS,
    float* __restrict__ nsrc, int n)
{
    __shared__ int cnt[BSZ];
    int b = blockIdx.x, tid = threadIdx.x;
    int nodeBase = b << BSHIFT;
    int nloc = min(BSZ, n - nodeBase);
    for (int i = tid; i < BSZ; i += 256) cnt[i] = 0;
    __syncthreads();
    int sbeg = b * capS, send = curS[b];
    for (int e = sbeg + tid; e < send; e += 256)
        atomicAdd(&cnt[srcStage[e]], 1);
    __syncthreads();
    for (int i = tid; i < nloc; i += 256)
        nsrc[nodeBase + i] = rsqrtf((float)max(cnt[i], 1));
}

// ---------------- MFMA GEMM: T(fp16) = (nsrc*X) @ W ----------------
// 64-row tile per block (4 waves, one 16-row tile each), N=64 = 4 col-tiles,
// K-loop in steps of 32 via v_mfma_f32_16x16x32_f16. nsrc folded into A staging.
// A and B fragments loaded with the same k-mapping -> any within-lane k
// permutation cancels between A and B; C/D layout: col=lane&15, row=(lane>>4)*4+reg.
template<int K>
__global__ __launch_bounds__(256) void gemm_mfma_kernel(
    const float* __restrict__ X, const float* __restrict__ nsrc,
    const float* __restrict__ W, __half* __restrict__ T, int n)
{
    constexpr int KP = K + 8;                 // padded halfs per row (16B-mult, bank-spread)
    __shared__ _Float16 sA[64 * KP];
    __shared__ _Float16 sW[64 * KP];          // W^T: [col][k]
    int tid = threadIdx.x;
    int brow = blockIdx.x * 64;

    // stage W^T (cvt fp32->fp16): thread t -> col c = t&63, k = (t>>6)*2 + j*8
    {
        int c = tid & 63;
        int kb = (tid >> 6) * 2;
        #pragma unroll
        for (int j = 0; j < K / 8; ++j) {
            int k = kb + j * 8;
            float w0 = W[k * 64 + c], w1 = W[(k + 1) * 64 + c];
            __half2 p = __floats2half2_rn(w0, w1);
            *(unsigned*)&sW[c * KP + k] = *(unsigned*)&p;
        }
    }
    // stage A rows (scaled by nsrc, cvt fp16)
    for (int i = tid; i < 64 * (K / 4); i += 256) {
        int rr = i / (K / 4);
        int kk = (i % (K / 4)) * 4;
        int row = brow + rr;
        float4 v = make_float4(0.f, 0.f, 0.f, 0.f);
        if (row < n) {
            v = ((const float4*)(X + (size_t)row * K))[kk >> 2];
            float s = nsrc[row];
            v.x *= s; v.y *= s; v.z *= s; v.w *= s;
        }
        __half2 p0 = __floats2half2_rn(v.x, v.y);
        __half2 p1 = __floats2half2_rn(v.z, v.w);
        uint2 u; u.x = *(unsigned*)&p0; u.y = *(unsigned*)&p1;
        *(uint2*)&sA[rr * KP + kk] = u;
    }
    __syncthreads();

    int l = tid & 63, wv = tid >> 6;
    int r = l & 15, g = l >> 4;
    const _Float16* aBase = sA + (wv * 16 + r) * KP + g * 8;
    const _Float16* bBase = sW + r * KP + g * 8;
    f32x4 acc0 = {0,0,0,0}, acc1 = {0,0,0,0}, acc2 = {0,0,0,0}, acc3 = {0,0,0,0};
    #pragma unroll
    for (int ks = 0; ks < K / 32; ++ks) {
        f16x8 a = *(const f16x8*)(aBase + ks * 32);
        f16x8 b0 = *(const f16x8*)(bBase + 0 * 16 * KP + ks * 32);
        f16x8 b1 = *(const f16x8*)(bBase + 1 * 16 * KP + ks * 32);
        f16x8 b2 = *(const f16x8*)(bBase + 2 * 16 * KP + ks * 32);
        f16x8 b3 = *(const f16x8*)(bBase + 3 * 16 * KP + ks * 32);
        acc0 = __builtin_amdgcn_mfma_f32_16x16x32_f16(a, b0, acc0, 0, 0, 0);
        acc1 = __builtin_amdgcn_mfma_f32_16x16x32_f16(a, b1, acc1, 0, 0, 0);
        acc2 = __builtin_amdgcn_mfma_f32_16x16x32_f16(a, b2, acc2, 0, 0, 0);
        acc3 = __builtin_amdgcn_mfma_f32_16x16x32_f16(a, b3, acc3, 0, 0, 0);
    }
    #pragma unroll
    for (int reg = 0; reg < 4; ++reg) {
        int row = brow + wv * 16 + g * 4 + reg;
        if (row < n) {
            __half* tp = T + (size_t)row * 64 + r;
            tp[0]  = __float2half(acc0[reg]);
            tp[16] = __float2half(acc1[reg]);
            tp[32] = __float2half(acc2[reg]);
            tp[48] = __float2half(acc3[reg]);
        }
    }
}

// ---------------- aggregation: out = agg(Tfp16) * ndst + b (opt relu) ----------------
// one wave per NPW consecutive nodes; lane = (g = lane>>5 edge group,
// f = lane&31 half2 chunk of the 128B row). Main pass = 8 edges, 4 independent
// 4B gathers in flight per lane; fp32 accumulate; cross-group reduce = ONE
// shfl_xor(32) per acc (replaces the old 24-op tree).
template<bool RELU>
__global__ __launch_bounds__(256) void aggregate_kernel(
    const unsigned* __restrict__ T2, const int* __restrict__ off,
    const int* __restrict__ esrc, const float* __restrict__ ndst,
    const float* __restrict__ bias, float* __restrict__ out, int n)
{
    int wave = (blockIdx.x * 256 + threadIdx.x) >> 6;
    int lane = threadIdx.x & 63;
    int f = lane & 31, g = lane >> 5;
    int node0 = wave * NPW;
    if (node0 >= n) return;
    float2 bb = ((const float2*)bias)[f];
    int nodeEnd = min(node0 + NPW, n);
    int beg = off[node0];
    for (int node = node0; node < nodeEnd; ++node) {
        int end = off[node + 1];
        float ax0 = 0.f, ay0 = 0.f, ax1 = 0.f, ay1 = 0.f;
        int e = beg;
        for (; e + 8 <= end; e += 8) {
            int s0 = esrc[e + g];
            int s1 = esrc[e + g + 2];
            int s2 = esrc[e + g + 4];
            int s3 = esrc[e + g + 6];
            unsigned v0 = T2[(size_t)s0 * 32 + f];
            unsigned v1 = T2[(size_t)s1 * 32 + f];
            unsigned v2 = T2[(size_t)s2 * 32 + f];
            unsigned v3 = T2[(size_t)s3 * 32 + f];
            float2 f0 = __half22float2(*(const __half2*)&v0);
            float2 f1 = __half22float2(*(const __half2*)&v1);
            float2 f2 = __half22float2(*(const __half2*)&v2);
            float2 f3 = __half22float2(*(const __half2*)&v3);
            ax0 += f0.x; ay0 += f0.y;
            ax1 += f1.x; ay1 += f1.y;
            ax0 += f2.x; ay0 += f2.y;
            ax1 += f3.x; ay1 += f3.y;
        }
        for (int idx = e + g; idx < end; idx += 2) {
            unsigned v = T2[(size_t)esrc[idx] * 32 + f];
            float2 ff = __half22float2(*(const __half2*)&v);
            ax0 += ff.x; ay0 += ff.y;
        }
        float ax = ax0 + ax1, ay = ay0 + ay1;
        ax += __shfl_xor(ax, 32, 64);
        ay += __shfl_xor(ay, 32, 64);
        if (g == 0) {
            float nd = ndst[node];
            float vx = ax * nd + bb.x;
            float vy = ay * nd + bb.y;
            if (RELU) { vx = fmaxf(vx, 0.f); vy = fmaxf(vy, 0.f); }
            ((float2*)out)[(size_t)node * 32 + f] = make_float2(vx, vy);
        }
        beg = end;
    }
}

extern "C" void kernel_launch(void* const* d_in, const int* in_sizes, int n_in,
                              void* d_out, int out_size, void* d_ws, size_t ws_size,
                              hipStream_t stream)
{
    const float* x  = (const float*)d_in[0];
    const int*   src = (const int*)d_in[1];
    const int*   dst = (const int*)d_in[2];
    const float* W1 = (const float*)d_in[3];
    const float* b1 = (const float*)d_in[4];
    const float* W2 = (const float*)d_in[5];
    const float* b2 = (const float*)d_in[6];

    const int FIN = 128;
    const int N = in_sizes[0] / FIN;
    const int E = in_sizes[1];
    const int NB = (N + BSZ - 1) >> BSHIFT;   // 98 for N=100k (<= NBCAP)

    // fixed bucket capacity: avg + 2048 (>> 16 sigma for a random graph), 256-aligned
    int cap = ((E + NB - 1) / NB + 2048 + 255) & ~255;

    char* ws = (char*)d_ws;
    size_t o = 0;
    auto carve = [&](size_t bytes) {
        void* p = ws + o;
        o = (o + bytes + 255) & ~((size_t)255);
        return p;
    };
    int* curS   = (int*)carve(NBCAP * 4);
    int* curD   = (int*)carve(NBCAP * 4);
    int* ebase  = (int*)carve((NBCAP + 1) * 4);
    int* off    = (int*)carve((size_t)(N + 1) * 4);
    float* nsrc = (float*)carve((size_t)N * 4);
    float* ndst = (float*)carve((size_t)N * 4);
    int* esrc   = (int*)carve((size_t)E * 4);
    size_t tbytes  = (size_t)N * 64 * 2;                  // fp16 t
    size_t stbytes = (size_t)NB * cap * 6 + 256;          // dstStage(4B) + srcStage(2B)
    void* tstage = carve(tbytes > stbytes ? tbytes : stbytes);
    // stage buffers alias t: both fully consumed (k3/k4) before gemm1 writes t
    __half* t = (__half*)tstage;
    unsigned* dstStage = (unsigned*)tstage;
    unsigned short* srcStage = (unsigned short*)((char*)tstage + (size_t)NB * cap * 4);

    float* h2 = (float*)d_out;
    float* h1 = (float*)d_out + (size_t)N * 64;

    int gb_e4k = (E + 4095) / 4096;
    int nwaves = (N + NPW - 1) / NPW;
    int gb_agg = (nwaves + 3) / 4;

    init_cursors_kernel<<<(NB + 255) / 256, 256, 0, stream>>>(curS, curD, NB, cap, cap);
    partition_kernel<<<gb_e4k, 256, 0, stream>>>(src, dst, curS, curD,
                                                 srcStage, dstStage, E);
    bucket_scan_kernel<<<1, 256, 0, stream>>>(curD, ebase, off, NB, cap, N, E);
    csr_build_kernel<<<NB, 256, 0, stream>>>(dstStage, curD, ebase, cap,
                                             off, ndst, esrc, N);
    dout_norm_kernel<<<NB, 256, 0, stream>>>(srcStage, curS, cap, nsrc, N);

    // layer 1: t = nsrc*(x@W1); h1 = relu(agg(t)*ndst + b1)
    gemm_mfma_kernel<128><<<(N + 63) / 64, 256, 0, stream>>>(x, nsrc, W1, t, N);
    aggregate_kernel<true><<<gb_agg, 256, 0, stream>>>((const unsigned*)t, off, esrc, ndst, b1, h1, N);
    // layer 2: t = nsrc*(h1@W2); h2 = agg(t)*ndst + b2
    gemm_mfma_kernel<64><<<(N + 63) / 64, 256, 0, stream>>>(h1, nsrc, W2, t, N);
    aggregate_kernel<false><<<gb_agg, 256, 0, stream>>>((const unsigned*)t, off, esrc, ndst, b2, h2, N);
}

// Round 8
// 181.787 us; speedup vs baseline: 1.2278x; 1.2278x over previous
//
#include <hip/hip_runtime.h>
#include <hip/hip_fp16.h>

#define NBCAP 256          // max buckets (static LDS arrays)
#define BSHIFT 10          // 1024 nodes per bucket
#define BSZ (1 << BSHIFT)
#define NPW 4              // nodes per wave in aggregate

typedef _Float16 f16x8 __attribute__((ext_vector_type(8)));
typedef float f32x4 __attribute__((ext_vector_type(4)));

__device__ __forceinline__ __half2 shfl_xor_h2(__half2 v, int m) {
    union { __half2 h; int i; } u; u.h = v;
    u.i = __shfl_xor(u.i, m, 64);
    return u.h;
}

// ---------------- k0: init bucket cursors to padded bases ----------------
__global__ __launch_bounds__(256) void init_cursors_kernel(
    int* __restrict__ curS, int* __restrict__ curD, int nb, int capS, int capD)
{
    int i = blockIdx.x * 256 + threadIdx.x;
    if (i < nb) { curS[i] = i * capS; curD[i] = i * capD; }
}

// ---------------- k1: partition edges by src-bucket and dst-bucket ----------------
// srcStage entry: local src id (ushort). dstStage entry: (dstLocal<<22)|src.
__global__ __launch_bounds__(256) void partition_kernel(
    const int* __restrict__ src, const int* __restrict__ dst,
    int* __restrict__ curS, int* __restrict__ curD,
    unsigned short* __restrict__ srcStage, unsigned* __restrict__ dstStage, int e)
{
    __shared__ int hS[NBCAP], hD[NBCAP], bS[NBCAP], bD[NBCAP];
    int tid = threadIdx.x;
    for (int i = tid; i < NBCAP; i += 256) { hS[i] = 0; hD[i] = 0; }
    __syncthreads();
    int blockBase = blockIdx.x * 4096;
    int s[16], d[16]; short rS[16], rD[16];
    #pragma unroll
    for (int k = 0; k < 16; ++k) {
        int i = blockBase + k * 256 + tid;
        if (i < e) {
            s[k] = src[i]; d[k] = dst[i];
            rS[k] = (short)atomicAdd(&hS[s[k] >> BSHIFT], 1);
            rD[k] = (short)atomicAdd(&hD[d[k] >> BSHIFT], 1);
        }
    }
    __syncthreads();
    for (int i = tid; i < NBCAP; i += 256) {
        bS[i] = hS[i] ? atomicAdd(&curS[i], hS[i]) : 0;
        bD[i] = hD[i] ? atomicAdd(&curD[i], hD[i]) : 0;
    }
    __syncthreads();
    #pragma unroll
    for (int k = 0; k < 16; ++k) {
        int i = blockBase + k * 256 + tid;
        if (i < e) {
            srcStage[bS[s[k] >> BSHIFT] + (int)rS[k]] = (unsigned short)(s[k] & (BSZ - 1));
            dstStage[bD[d[k] >> BSHIFT] + (int)rD[k]] =
                ((unsigned)(d[k] & (BSZ - 1)) << 22) | (unsigned)s[k];
        }
    }
}

// ---------------- k2: exact dst-bucket bases from cursors (single block) ----------------
__global__ __launch_bounds__(256) void bucket_scan_kernel(
    const int* __restrict__ curD, int* __restrict__ ebase,
    int* __restrict__ off, int nb, int capD, int n, int e)
{
    __shared__ int lds[256];
    int tid = threadIdx.x;
    int v = (tid < nb) ? (curD[tid] - tid * capD) : 0;
    lds[tid] = v;
    __syncthreads();
    for (int o = 1; o < 256; o <<= 1) {
        int a = (tid >= o) ? lds[tid - o] : 0;
        __syncthreads();
        lds[tid] += a;
        __syncthreads();
    }
    if (tid < nb) ebase[tid] = lds[tid] - v;
    if (tid == 0) { ebase[nb] = e; off[n] = e; }
}

// ---------------- k3: merged per-bucket pass ----------------
// blocks [0,nb): din hist + CSR offsets + ndst + esrc scatter (dst buckets)
// blocks [nb,2nb): dout hist -> nsrc (src buckets)
__global__ __launch_bounds__(256) void csr_norm_kernel(
    const unsigned* __restrict__ dstStage, const unsigned short* __restrict__ srcStage,
    const int* __restrict__ curS, const int* __restrict__ curD,
    const int* __restrict__ ebase, int cap,
    int* __restrict__ off, float* __restrict__ ndst, float* __restrict__ nsrc,
    int* __restrict__ esrc, int n, int nb)
{
    __shared__ int cnt[BSZ];
    __shared__ int wsum[256];
    int b = blockIdx.x, tid = threadIdx.x;

    if (b >= nb) {
        // ---- dout_norm part ----
        b -= nb;
        int nodeBase = b << BSHIFT;
        int nloc = min(BSZ, n - nodeBase);
        for (int i = tid; i < BSZ; i += 256) cnt[i] = 0;
        __syncthreads();
        int sbeg = b * cap, send = curS[b];
        for (int e = sbeg + tid; e < send; e += 256)
            atomicAdd(&cnt[srcStage[e]], 1);
        __syncthreads();
        for (int i = tid; i < nloc; i += 256)
            nsrc[nodeBase + i] = rsqrtf((float)max(cnt[i], 1));
        return;
    }

    // ---- csr_build part ----
    int nodeBase = b << BSHIFT;
    int nloc = min(BSZ, n - nodeBase);
    int sbeg = b * cap;
    int send = curD[b];
    int ebeg = ebase[b];
    for (int i = tid; i < BSZ; i += 256) cnt[i] = 0;
    __syncthreads();
    for (int e = sbeg + tid; e < send; e += 256)
        atomicAdd(&cnt[dstStage[e] >> 22], 1);
    __syncthreads();
    int c0 = cnt[tid * 4], c1 = cnt[tid * 4 + 1], c2 = cnt[tid * 4 + 2], c3 = cnt[tid * 4 + 3];
    int tsum = c0 + c1 + c2 + c3;
    wsum[tid] = tsum;
    __syncthreads();
    for (int o = 1; o < 256; o <<= 1) {
        int a = (tid >= o) ? wsum[tid - o] : 0;
        __syncthreads();
        wsum[tid] += a;
        __syncthreads();
    }
    int excl = wsum[tid] - tsum;
    int pj[4] = { excl, excl + c0, excl + c0 + c1, excl + c0 + c1 + c2 };
    int cj[4] = { c0, c1, c2, c3 };
    #pragma unroll
    for (int j = 0; j < 4; ++j) {
        int node = tid * 4 + j;
        if (node < nloc) {
            off[nodeBase + node]  = ebeg + pj[j];
            ndst[nodeBase + node] = rsqrtf((float)max(cj[j], 1));
        }
        cnt[node] = pj[j];   // becomes LDS cursor
    }
    __syncthreads();
    for (int e = sbeg + tid; e < send; e += 256) {
        unsigned u = dstStage[e];
        int lp = atomicAdd(&cnt[u >> 22], 1);
        esrc[ebeg + lp] = (int)(u & 0x3FFFFFu);
    }
}

// ---------------- MFMA GEMM: T(fp16) = (nsrc*X) @ W ----------------
// 64-row tile per block (4 waves, one 16-row tile each), N=64 = 4 col-tiles,
// K-loop in steps of 32 via v_mfma_f32_16x16x32_f16. nsrc folded into A staging.
// A and B fragments loaded with the same k-mapping -> any within-lane k
// permutation cancels between A and B; C/D layout: col=lane&15, row=(lane>>4)*4+reg.
template<int K>
__global__ __launch_bounds__(256) void gemm_mfma_kernel(
    const float* __restrict__ X, const float* __restrict__ nsrc,
    const float* __restrict__ W, __half* __restrict__ T, int n)
{
    constexpr int KP = K + 8;                 // padded halfs per row (16B-mult, bank-spread)
    __shared__ _Float16 sA[64 * KP];
    __shared__ _Float16 sW[64 * KP];          // W^T: [col][k]
    int tid = threadIdx.x;
    int brow = blockIdx.x * 64;

    // stage W^T (cvt fp32->fp16): thread t -> col c = t&63, k = (t>>6)*2 + j*8
    {
        int c = tid & 63;
        int kb = (tid >> 6) * 2;
        #pragma unroll
        for (int j = 0; j < K / 8; ++j) {
            int k = kb + j * 8;
            float w0 = W[k * 64 + c], w1 = W[(k + 1) * 64 + c];
            __half2 p = __floats2half2_rn(w0, w1);
            *(unsigned*)&sW[c * KP + k] = *(unsigned*)&p;
        }
    }
    // stage A rows (scaled by nsrc, cvt fp16)
    for (int i = tid; i < 64 * (K / 4); i += 256) {
        int rr = i / (K / 4);
        int kk = (i % (K / 4)) * 4;
        int row = brow + rr;
        float4 v = make_float4(0.f, 0.f, 0.f, 0.f);
        if (row < n) {
            v = ((const float4*)(X + (size_t)row * K))[kk >> 2];
            float s = nsrc[row];
            v.x *= s; v.y *= s; v.z *= s; v.w *= s;
        }
        __half2 p0 = __floats2half2_rn(v.x, v.y);
        __half2 p1 = __floats2half2_rn(v.z, v.w);
        uint2 u; u.x = *(unsigned*)&p0; u.y = *(unsigned*)&p1;
        *(uint2*)&sA[rr * KP + kk] = u;
    }
    __syncthreads();

    int l = tid & 63, wv = tid >> 6;
    int r = l & 15, g = l >> 4;
    const _Float16* aBase = sA + (wv * 16 + r) * KP + g * 8;
    const _Float16* bBase = sW + r * KP + g * 8;
    f32x4 acc0 = {0,0,0,0}, acc1 = {0,0,0,0}, acc2 = {0,0,0,0}, acc3 = {0,0,0,0};
    #pragma unroll
    for (int ks = 0; ks < K / 32; ++ks) {
        f16x8 a = *(const f16x8*)(aBase + ks * 32);
        f16x8 b0 = *(const f16x8*)(bBase + 0 * 16 * KP + ks * 32);
        f16x8 b1 = *(const f16x8*)(bBase + 1 * 16 * KP + ks * 32);
        f16x8 b2 = *(const f16x8*)(bBase + 2 * 16 * KP + ks * 32);
        f16x8 b3 = *(const f16x8*)(bBase + 3 * 16 * KP + ks * 32);
        acc0 = __builtin_amdgcn_mfma_f32_16x16x32_f16(a, b0, acc0, 0, 0, 0);
        acc1 = __builtin_amdgcn_mfma_f32_16x16x32_f16(a, b1, acc1, 0, 0, 0);
        acc2 = __builtin_amdgcn_mfma_f32_16x16x32_f16(a, b2, acc2, 0, 0, 0);
        acc3 = __builtin_amdgcn_mfma_f32_16x16x32_f16(a, b3, acc3, 0, 0, 0);
    }
    #pragma unroll
    for (int reg = 0; reg < 4; ++reg) {
        int row = brow + wv * 16 + g * 4 + reg;
        if (row < n) {
            __half* tp = T + (size_t)row * 64 + r;
            tp[0]  = __float2half(acc0[reg]);
            tp[16] = __float2half(acc1[reg]);
            tp[32] = __float2half(acc2[reg]);
            tp[48] = __float2half(acc3[reg]);
        }
    }
}

// ---------------- aggregation: out = agg(Tfp16) * ndst + b (opt relu) ----------------
// one wave per NPW consecutive nodes; 16 edges per main-loop pass:
// lane = (edge-group g = lane>>3, feat-chunk f = lane&7); uint4 loads (1KB/instr),
// 2 independent gathers in flight. Accumulation in packed fp16 (__hadd2);
// cross-group reduce = 3-level shfl_xor on 4 half2 regs; fp32 only at epilogue.
template<bool RELU>
__global__ __launch_bounds__(256) void aggregate_kernel(
    const uint4* __restrict__ T4, const int* __restrict__ off,
    const int* __restrict__ esrc, const float* __restrict__ ndst,
    const float* __restrict__ bias, float* __restrict__ out, int n)
{
    int wave = (blockIdx.x * 256 + threadIdx.x) >> 6;
    int lane = threadIdx.x & 63;
    int g = lane >> 3, f = lane & 7;
    int node0 = wave * NPW;
    if (node0 >= n) return;
    float4 bb0 = ((const float4*)bias)[f * 2];
    float4 bb1 = ((const float4*)bias)[f * 2 + 1];
    int nodeEnd = min(node0 + NPW, n);
    int beg = off[node0];
    for (int node = node0; node < nodeEnd; ++node) {
        int end = off[node + 1];
        __half2 z; *(unsigned*)&z = 0u;
        __half2 h0 = z, h1 = z, h2 = z, h3 = z;
        int e = beg;
        for (; e + 16 <= end; e += 16) {
            int sa = esrc[e + g], sb = esrc[e + 8 + g];
            uint4 va = T4[(size_t)sa * 8 + f];
            uint4 vb = T4[(size_t)sb * 8 + f];
            h0 = __hadd2(h0, __hadd2(*(const __half2*)&va.x, *(const __half2*)&vb.x));
            h1 = __hadd2(h1, __hadd2(*(const __half2*)&va.y, *(const __half2*)&vb.y));
            h2 = __hadd2(h2, __hadd2(*(const __half2*)&va.z, *(const __half2*)&vb.z));
            h3 = __hadd2(h3, __hadd2(*(const __half2*)&va.w, *(const __half2*)&vb.w));
        }
        for (; e + 8 <= end; e += 8) {
            int s = esrc[e + g];
            uint4 v = T4[(size_t)s * 8 + f];
            h0 = __hadd2(h0, *(const __half2*)&v.x);
            h1 = __hadd2(h1, *(const __half2*)&v.y);
            h2 = __hadd2(h2, *(const __half2*)&v.z);
            h3 = __hadd2(h3, *(const __half2*)&v.w);
        }
        if (e + g < end) {
            int s = esrc[e + g];
            uint4 v = T4[(size_t)s * 8 + f];
            h0 = __hadd2(h0, *(const __half2*)&v.x);
            h1 = __hadd2(h1, *(const __half2*)&v.y);
            h2 = __hadd2(h2, *(const __half2*)&v.z);
            h3 = __hadd2(h3, *(const __half2*)&v.w);
        }
        #pragma unroll
        for (int m = 8; m <= 32; m <<= 1) {
            h0 = __hadd2(h0, shfl_xor_h2(h0, m));
            h1 = __hadd2(h1, shfl_xor_h2(h1, m));
            h2 = __hadd2(h2, shfl_xor_h2(h2, m));
            h3 = __hadd2(h3, shfl_xor_h2(h3, m));
        }
        if (g == 0) {
            float2 f0 = __half22float2(h0), f1 = __half22float2(h1);
            float2 f2 = __half22float2(h2), f3 = __half22float2(h3);
            float nd = ndst[node];
            float4 o0 = make_float4(f0.x * nd + bb0.x, f0.y * nd + bb0.y,
                                    f1.x * nd + bb0.z, f1.y * nd + bb0.w);
            float4 o1 = make_float4(f2.x * nd + bb1.x, f2.y * nd + bb1.y,
                                    f3.x * nd + bb1.z, f3.y * nd + bb1.w);
            if (RELU) {
                o0.x = fmaxf(o0.x, 0.f); o0.y = fmaxf(o0.y, 0.f);
                o0.z = fmaxf(o0.z, 0.f); o0.w = fmaxf(o0.w, 0.f);
                o1.x = fmaxf(o1.x, 0.f); o1.y = fmaxf(o1.y, 0.f);
                o1.z = fmaxf(o1.z, 0.f); o1.w = fmaxf(o1.w, 0.f);
            }
            ((float4*)out)[(size_t)node * 16 + f * 2]     = o0;
            ((float4*)out)[(size_t)node * 16 + f * 2 + 1] = o1;
        }
        beg = end;
    }
}

extern "C" void kernel_launch(void* const* d_in, const int* in_sizes, int n_in,
                              void* d_out, int out_size, void* d_ws, size_t ws_size,
                              hipStream_t stream)
{
    const float* x  = (const float*)d_in[0];
    const int*   src = (const int*)d_in[1];
    const int*   dst = (const int*)d_in[2];
    const float* W1 = (const float*)d_in[3];
    const float* b1 = (const float*)d_in[4];
    const float* W2 = (const float*)d_in[5];
    const float* b2 = (const float*)d_in[6];

    const int FIN = 128;
    const int N = in_sizes[0] / FIN;
    const int E = in_sizes[1];
    const int NB = (N + BSZ - 1) >> BSHIFT;   // 98 for N=100k (<= NBCAP)

    // fixed bucket capacity: avg + 2048 (>> 16 sigma for a random graph), 256-aligned
    int cap = ((E + NB - 1) / NB + 2048 + 255) & ~255;

    char* ws = (char*)d_ws;
    size_t o = 0;
    auto carve = [&](size_t bytes) {
        void* p = ws + o;
        o = (o + bytes + 255) & ~((size_t)255);
        return p;
    };
    int* curS   = (int*)carve(NBCAP * 4);
    int* curD   = (int*)carve(NBCAP * 4);
    int* ebase  = (int*)carve((NBCAP + 1) * 4);
    int* off    = (int*)carve((size_t)(N + 1) * 4);
    float* nsrc = (float*)carve((size_t)N * 4);
    float* ndst = (float*)carve((size_t)N * 4);
    int* esrc   = (int*)carve((size_t)E * 4);
    size_t tbytes  = (size_t)N * 64 * 2;                  // fp16 t
    size_t stbytes = (size_t)NB * cap * 6 + 256;          // dstStage(4B) + srcStage(2B)
    void* tstage = carve(tbytes > stbytes ? tbytes : stbytes);
    // stage buffers alias t: both fully consumed (k3) before gemm1 writes t
    __half* t = (__half*)tstage;
    unsigned* dstStage = (unsigned*)tstage;
    unsigned short* srcStage = (unsigned short*)((char*)tstage + (size_t)NB * cap * 4);

    float* h2 = (float*)d_out;
    float* h1 = (float*)d_out + (size_t)N * 64;

    int gb_e4k = (E + 4095) / 4096;
    int nwaves = (N + NPW - 1) / NPW;
    int gb_agg = (nwaves + 3) / 4;

    init_cursors_kernel<<<(NB + 255) / 256, 256, 0, stream>>>(curS, curD, NB, cap, cap);
    partition_kernel<<<gb_e4k, 256, 0, stream>>>(src, dst, curS, curD,
                                                 srcStage, dstStage, E);
    bucket_scan_kernel<<<1, 256, 0, stream>>>(curD, ebase, off, NB, cap, N, E);
    csr_norm_kernel<<<2 * NB, 256, 0, stream>>>(dstStage, srcStage, curS, curD,
                                                ebase, cap, off, ndst, nsrc, esrc, N, NB);

    // layer 1: t = nsrc*(x@W1); h1 = relu(agg(t)*ndst + b1)
    gemm_mfma_kernel<128><<<(N + 63) / 64, 256, 0, stream>>>(x, nsrc, W1, t, N);
    aggregate_kernel<true><<<gb_agg, 256, 0, stream>>>((const uint4*)t, off, esrc, ndst, b1, h1, N);
    // layer 2: t = nsrc*(h1@W2); h2 = agg(t)*ndst + b2
    gemm_mfma_kernel<64><<<(N + 63) / 64, 256, 0, stream>>>(h1, nsrc, W2, t, N);
    aggregate_kernel<false><<<gb_agg, 256, 0, stream>>>((const uint4*)t, off, esrc, ndst, b2, h2, N);
}